// Round 3
// baseline (354.899 us; speedup 1.0000x reference)
//
#include <hip/hip_runtime.h>

// PointPillarsScatter: out(B=4, C=64, NY=496, NX=432) <- scatter of
// voxel_features(N=64000, 64) f32 at coors(N,4)=[b,z,y,x]. Duplicates: last wins.
//
// Inverse-index gather, v2:
//   pass 0: memset winner map ws[B*NPIX] = -1        (hipMemsetAsync 0xFF, 3.4 MB)
//   pass 1 (pps_prep): transpose vf(64000,64) -> vfT(64,64000) in d_ws
//                      + atomicMax(&ws[b*NPIX+y*NX+x], n)  (last dup wins = np semantics)
//   pass 2 (pps_gather): per (b,c,pix8): n = ws[..]; out = n>=0 ? vfT[c][n] : 0
//     - c is wave-uniform -> random reads confined to one 256 KB vfT row (L2-resident)
//     - output stores are non-temporal (219 MB streamed once, never re-read;
//       keeps vfT/ws resident in L2)

#define C_CH 64
#define NY_ 496
#define NX_ 432
#define NPIX (NY_ * NX_)      // 214272
#define NVOX 64000
#define BATCH_ 4
#define PIX8 (NPIX / 8)       // 26784 groups of 8 pixels per (b,c) plane

typedef float f32x4 __attribute__((ext_vector_type(4)));  // NT-store-compatible 16B vector

// Transpose vf -> vfT (64 x 64000) and resolve winners.
// grid: 1000 blocks x 256 threads; block k transposes n-rows [64k, 64k+64).
__global__ void pps_prep(const float* __restrict__ vf,
                         const int* __restrict__ coors,
                         int* __restrict__ ws,
                         float* __restrict__ vfT) {
    __shared__ float tile[64][65];  // +1 pad: conflict-free column reads

    // winner resolution (blocks 0..249 carry the 64000 atomics)
    int gid = blockIdx.x * 256 + threadIdx.x;
    if (gid < NVOX) {
        const int4 cv = reinterpret_cast<const int4*>(coors)[gid];  // [b,z,y,x]
        atomicMax(&ws[cv.x * NPIX + cv.z * NX_ + cv.w], gid);
    }

    int n0 = blockIdx.x * 64;
    int tr = threadIdx.x >> 2;          // 0..63: n-row within tile
    int tc = (threadIdx.x & 3) * 16;    // col start (channel), 16 floats

    // coalesced load: wave covers 16 full vf rows (4 KB contiguous)
    const float4* src = reinterpret_cast<const float4*>(vf + (long)(n0 + tr) * C_CH + tc);
    #pragma unroll
    for (int j = 0; j < 4; ++j) {
        float4 v = src[j];
        tile[tr][tc + j * 4 + 0] = v.x;
        tile[tr][tc + j * 4 + 1] = v.y;
        tile[tr][tc + j * 4 + 2] = v.z;
        tile[tr][tc + j * 4 + 3] = v.w;
    }
    __syncthreads();

    // transposed write: thread t -> channel c = t>>2, n-chunk (t&3)*16
    int c = threadIdx.x >> 2;
    int ns = (threadIdx.x & 3) * 16;
    float* dst = vfT + (long)c * NVOX + n0 + ns;
    #pragma unroll
    for (int j = 0; j < 4; ++j) {
        float4 v;
        v.x = tile[ns + j * 4 + 0][c];
        v.y = tile[ns + j * 4 + 1][c];
        v.z = tile[ns + j * 4 + 2][c];
        v.w = tile[ns + j * 4 + 3][c];
        reinterpret_cast<float4*>(dst)[j] = v;  // coalesced 16B
    }
}

__global__ void pps_gather(const float* __restrict__ vfT,
                           const int* __restrict__ ws,
                           float* __restrict__ out) {
    // One thread per 8 consecutive x of one (b,c) plane.
    int tid = blockIdx.x * blockDim.x + threadIdx.x;
    int bc = tid / PIX8;                 // const divisor -> magic mul
    int p8 = tid - bc * PIX8;
    int b = bc >> 6;
    int c = bc & 63;
    int pix = p8 * 8;

    const int4* wp = reinterpret_cast<const int4*>(&ws[b * NPIX + pix]);
    const int4 w0 = wp[0];
    const int4 w1 = wp[1];
    const float* __restrict__ row = vfT + (long)c * NVOX;  // 256 KB, wave-uniform c

    f32x4 o0, o1;
    o0.x = (w0.x >= 0) ? row[w0.x] : 0.0f;
    o0.y = (w0.y >= 0) ? row[w0.y] : 0.0f;
    o0.z = (w0.z >= 0) ? row[w0.z] : 0.0f;
    o0.w = (w0.w >= 0) ? row[w0.w] : 0.0f;
    o1.x = (w1.x >= 0) ? row[w1.x] : 0.0f;
    o1.y = (w1.y >= 0) ? row[w1.y] : 0.0f;
    o1.z = (w1.z >= 0) ? row[w1.z] : 0.0f;
    o1.w = (w1.w >= 0) ? row[w1.w] : 0.0f;

    f32x4* op = reinterpret_cast<f32x4*>(&out[(long)bc * NPIX + pix]);
    __builtin_nontemporal_store(o0, op);      // streamed, never re-read
    __builtin_nontemporal_store(o1, op + 1);
}

extern "C" void kernel_launch(void* const* d_in, const int* in_sizes, int n_in,
                              void* d_out, int out_size, void* d_ws, size_t ws_size,
                              hipStream_t stream) {
    const float* vf = (const float*)d_in[0];   // (64000, 64) f32
    const int* coors = (const int*)d_in[1];    // (64000, 4)  i32
    float* out = (float*)d_out;                // (4, 64, 496, 432) f32
    int* ws = (int*)d_ws;                      // [0, 857088) ints: winner map (3.4 MB)
    float* vfT = (float*)(ws + (size_t)BATCH_ * NPIX);  // 16.4 MB transposed features

    // winner map = -1 everywhere (0xFF bytes == int -1)
    (void)hipMemsetAsync(ws, 0xFF, (size_t)BATCH_ * NPIX * sizeof(int), stream);

    // transpose + winner resolution
    pps_prep<<<NVOX / 64, 256, 0, stream>>>(vf, coors, ws, vfT);

    // coalesced NT gather into output
    {
        int total = BATCH_ * C_CH * PIX8;      // 6,856,704 threads
        pps_gather<<<total / 256, 256, 0, stream>>>(vfT, ws, out);
    }
}

// Round 4
// 241.739 us; speedup vs baseline: 1.4681x; 1.4681x over previous
//
#include <hip/hip_runtime.h>

// PointPillarsScatter: out(B=4, C=64, NY=496, NX=432) <- scatter of
// voxel_features(N=64000, 64) f32 at coors(N,4)=[b,z,y,x]. Duplicates: last wins.
//
// v3: direct gather + XCD-ownership swizzle (no transpose, no NT stores).
//   pass 0: memset winner map ws[B*NPIX] = -1   (hipMemsetAsync 0xFF, 3.4 MB)
//   pass 1 (pps_winners): atomicMax(&ws[b*NPIX+y*NX+x], n)  -> last dup wins (np semantics)
//   pass 2 (pps_gather): 4 px/thread; bijective XCD swizzle gives each XCD
//     3348 consecutive virtual blocks = 32 consecutive (b,c) planes =
//     channels [c0,c0+32) of one batch. Its random vf reads then touch only
//     16000 voxels x 128B = 2.05 MB + 0.86 MB ws slice -> L2-resident.
//     Stores: one float4 per thread -> 1KB contiguous per wave instruction,
//     regular write-back stores (full-line, no RMW).

#define C_CH 64
#define NY_ 496
#define NX_ 432
#define NPIX (NY_ * NX_)      // 214272
#define NVOX 64000
#define BATCH_ 4
#define PIX4 (NPIX / 4)       // 53568 float4 groups per (b,c) plane

typedef float f32x4 __attribute__((ext_vector_type(4)));

__global__ void pps_winners(const int* __restrict__ coors, int* __restrict__ ws) {
    int i = blockIdx.x * blockDim.x + threadIdx.x;
    if (i >= NVOX) return;
    const int4 cv = reinterpret_cast<const int4*>(coors)[i];  // [b, z, y, x]
    atomicMax(&ws[cv.x * NPIX + cv.z * NX_ + cv.w], i);  // ws pre-set to -1
}

__global__ void __launch_bounds__(256) pps_gather(const float* __restrict__ vf,
                                                  const int* __restrict__ ws,
                                                  float* __restrict__ out) {
    // nwg = 53568 = 8 * 6696. Bijective XCD swizzle: XCD k owns virtual blocks
    // [k*6696, (k+1)*6696) = a contiguous span of 32 (b,c) planes.
    int wg = (blockIdx.x & 7) * (53568 / 8) + (blockIdx.x >> 3);
    int tid = wg * 256 + threadIdx.x;

    int bc = tid / PIX4;                 // const divisor -> magic mul
    int p4 = tid - bc * PIX4;
    int b = bc >> 6;
    int c = bc & 63;
    int pix = p4 * 4;

    const int4 w = *reinterpret_cast<const int4*>(&ws[b * NPIX + pix]);  // 16B coalesced
    f32x4 o;
    o.x = (w.x >= 0) ? vf[(long)w.x * C_CH + c] : 0.0f;
    o.y = (w.y >= 0) ? vf[(long)w.y * C_CH + c] : 0.0f;
    o.z = (w.z >= 0) ? vf[(long)w.z * C_CH + c] : 0.0f;
    o.w = (w.w >= 0) ? vf[(long)w.w * C_CH + c] : 0.0f;

    // wave store: 64 lanes x 16B contiguous = 1KB, full 64B lines in one instr
    *reinterpret_cast<f32x4*>(&out[(long)bc * NPIX + pix]) = o;
}

extern "C" void kernel_launch(void* const* d_in, const int* in_sizes, int n_in,
                              void* d_out, int out_size, void* d_ws, size_t ws_size,
                              hipStream_t stream) {
    const float* vf = (const float*)d_in[0];   // (64000, 64) f32
    const int* coors = (const int*)d_in[1];    // (64000, 4)  i32
    float* out = (float*)d_out;                // (4, 64, 496, 432) f32
    int* ws = (int*)d_ws;                      // winner map: BATCH_*NPIX ints = 3.4 MB

    // winner map = -1 everywhere (0xFF bytes == int -1)
    (void)hipMemsetAsync(ws, 0xFF, (size_t)BATCH_ * NPIX * sizeof(int), stream);

    pps_winners<<<(NVOX + 255) / 256, 256, 0, stream>>>(coors, ws);

    // 4 px/thread: total threads = 4*64*PIX4 = 13,713,408 -> 53568 blocks
    pps_gather<<<BATCH_ * C_CH * PIX4 / 256, 256, 0, stream>>>(vf, ws, out);
}

// Round 5
// 241.652 us; speedup vs baseline: 1.4686x; 1.0004x over previous
//
#include <hip/hip_runtime.h>

// PointPillarsScatter: out(B=4, C=64, NY=496, NX=432) <- scatter of
// voxel_features(N=64000, 64) f32 at coors(N,4)=[b,z,y,x]. Duplicates: last wins.
//
// v4: channel-group-major gather (full-line vf reads).
//   pass 0: memset winner map ws[B*NPIX] = -1   (hipMemsetAsync 0xFF, 3.4 MB)
//   pass 1 (pps_winners): atomicMax(&ws[b*NPIX+y*NX+x], n) -> last dup wins (np)
//   pass 2 (pps_gather): thread = (b, cg, pixel). Lane reads winner once, then
//     vf[w*64 + cg*16 .. +16) = ONE full 64B line, all 16 values used
//     (kills the 16x L2->L1 line re-fetch of the per-(pixel,channel) layout).
//     16 scalar NT stores: each wave instr = 256B contiguous = 4 full lines
//     (NT safe: full-line coverage per instruction; keeps 219MB stream out of
//     L2 so the ~2MB/XCD vf+ws working set stays resident).
//   XCD swizzle: 13392 blocks = 8*1674; each XCD owns 2 consecutive (b,cg)
//     panels -> vf lines (1MB) + ws slice (0.86MB) L2-resident.

#define C_CH 64
#define NY_ 496
#define NX_ 432
#define NPIX (NY_ * NX_)      // 214272 = 837 * 256
#define NVOX 64000
#define BATCH_ 4
#define PBLK 837              // 256-pixel blocks per plane
#define NWG (BATCH_ * 4 * PBLK)  // 13392 = 8 * 1674

typedef float f32x4 __attribute__((ext_vector_type(4)));

__global__ void pps_winners(const int* __restrict__ coors, int* __restrict__ ws) {
    int i = blockIdx.x * blockDim.x + threadIdx.x;
    if (i >= NVOX) return;
    const int4 cv = reinterpret_cast<const int4*>(coors)[i];  // [b, z, y, x]
    atomicMax(&ws[cv.x * NPIX + cv.z * NX_ + cv.w], i);  // ws pre-set to -1
}

__global__ void __launch_bounds__(256) pps_gather(const float* __restrict__ vf,
                                                  const int* __restrict__ ws,
                                                  float* __restrict__ out) {
    // bijective XCD swizzle: XCD k owns virtual wgs [k*1674, (k+1)*1674)
    int bid = blockIdx.x;
    int wg = (bid & 7) * (NWG / 8) + (bid >> 3);

    int blk = wg % PBLK;          // pixel block within plane (const divisor)
    int bcg = wg / PBLK;          // 0..15
    int cg = bcg & 3;             // channel group (16 ch)
    int b = bcg >> 2;             // batch

    int pix = blk * 256 + threadIdx.x;
    int w = ws[b * NPIX + pix];   // coalesced 4B/lane

    f32x4 v0 = {0.f, 0.f, 0.f, 0.f}, v1 = v0, v2 = v0, v3 = v0;
    if (w >= 0) {
        // one full 64B line per lane, all 16 floats used
        const f32x4* src = reinterpret_cast<const f32x4*>(vf + (long)w * C_CH + cg * 16);
        v0 = src[0]; v1 = src[1]; v2 = src[2]; v3 = src[3];
    }

    float* o = out + ((long)(b * C_CH + cg * 16)) * NPIX + pix;
    // 16 NT scalar stores; each instruction: 64 lanes x 4B = 256B contiguous
    __builtin_nontemporal_store(v0.x, o);
    __builtin_nontemporal_store(v0.y, o + 1L * NPIX);
    __builtin_nontemporal_store(v0.z, o + 2L * NPIX);
    __builtin_nontemporal_store(v0.w, o + 3L * NPIX);
    __builtin_nontemporal_store(v1.x, o + 4L * NPIX);
    __builtin_nontemporal_store(v1.y, o + 5L * NPIX);
    __builtin_nontemporal_store(v1.z, o + 6L * NPIX);
    __builtin_nontemporal_store(v1.w, o + 7L * NPIX);
    __builtin_nontemporal_store(v2.x, o + 8L * NPIX);
    __builtin_nontemporal_store(v2.y, o + 9L * NPIX);
    __builtin_nontemporal_store(v2.z, o + 10L * NPIX);
    __builtin_nontemporal_store(v2.w, o + 11L * NPIX);
    __builtin_nontemporal_store(v3.x, o + 12L * NPIX);
    __builtin_nontemporal_store(v3.y, o + 13L * NPIX);
    __builtin_nontemporal_store(v3.z, o + 14L * NPIX);
    __builtin_nontemporal_store(v3.w, o + 15L * NPIX);
}

extern "C" void kernel_launch(void* const* d_in, const int* in_sizes, int n_in,
                              void* d_out, int out_size, void* d_ws, size_t ws_size,
                              hipStream_t stream) {
    const float* vf = (const float*)d_in[0];   // (64000, 64) f32
    const int* coors = (const int*)d_in[1];    // (64000, 4)  i32
    float* out = (float*)d_out;                // (4, 64, 496, 432) f32
    int* ws = (int*)d_ws;                      // winner map: BATCH_*NPIX ints = 3.4 MB

    // winner map = -1 everywhere (0xFF bytes == int -1)
    (void)hipMemsetAsync(ws, 0xFF, (size_t)BATCH_ * NPIX * sizeof(int), stream);

    pps_winners<<<(NVOX + 255) / 256, 256, 0, stream>>>(coors, ws);

    pps_gather<<<NWG, 256, 0, stream>>>(vf, ws, out);
}